// Round 3
// baseline (178.230 us; speedup 1.0000x reference)
//
#include <hip/hip_runtime.h>
#include <hip/hip_bf16.h>

typedef __attribute__((ext_vector_type(8))) short short8;
typedef __attribute__((ext_vector_type(4))) float f32x4;

#define NR 256
#define CC 256

__device__ __forceinline__ unsigned short f2bf(float x) {
    union { float f; unsigned int u; } v; v.f = x;
    unsigned int r = v.u + 0x7FFFu + ((v.u >> 16) & 1u);
    return (unsigned short)(r >> 16);
}

__device__ __forceinline__ unsigned int pk2bf(float a, float b) {
    __hip_bfloat162 h = __float22bfloat162_rn(make_float2(a, b));
    union { __hip_bfloat162 h; unsigned int u; } cv; cv.h = h;
    return cv.u;
}

// ---------------- Qpp[ksl][b][n] = partial Q @ Wq ----------------
__global__ __launch_bounds__(256) void qp_kernel(
    const float* __restrict__ Q, const float* __restrict__ Wq,
    float* __restrict__ Qpp)
{
    const int ksl = blockIdx.x, b = blockIdx.y;
    const int n = threadIdx.x;
    __shared__ float qs[256];
    qs[n] = Q[b * 1024 + ksl * 256 + n];
    __syncthreads();
    float acc = 0.f;
    #pragma unroll 4
    for (int d = 0; d < 256; ++d) acc += qs[d] * Wq[(size_t)(ksl * 256 + d) * 256 + n];
    Qpp[(ksl * 4 + b) * 256 + n] = acc;
}

// ---------------- pack Wv into MFMA B-frag layout (bf16), K padded to 2080 ----------------
__global__ __launch_bounds__(256) void wvp_pack_kernel(
    const float* __restrict__ Wv, unsigned short* __restrict__ wvp)
{
    __shared__ float tile[32][260];
    const int ks = blockIdx.x;   // 0..64
    const int tid = threadIdx.x;
    for (int idx = tid; idx < 32 * 256; idx += 256) {
        int cr = idx >> 8, n = idx & 255;
        int c = ks * 32 + cr;
        tile[cr][n] = (c < 2056) ? Wv[(size_t)c * 256 + n] : 0.f;
    }
    __syncthreads();
    #pragma unroll
    for (int q = 0; q < 4; ++q) {
        int t2 = tid * 4 + q;
        int nt = t2 >> 6, l = t2 & 63;
        int gg = l >> 4, jj = l & 15;
        short8 s;
        #pragma unroll
        for (int e = 0; e < 8; ++e)
            s[e] = (short)f2bf(tile[gg * 8 + e][nt * 16 + jj]);
        *(short8*)&wvp[((size_t)(ks * 16 + nt) * 64 + l) * 8] = s;
    }
}

// ---------------- pack MLP weights into MFMA fragment layout (bf16) ----------------
__global__ __launch_bounds__(256) void pack_kernel(
    const float* __restrict__ W01, const float* __restrict__ W1,
    const float* __restrict__ W02, const float* __restrict__ W2,
    unsigned short* __restrict__ wpa, unsigned short* __restrict__ wpb)
{
    int t = blockIdx.x * 256 + threadIdx.x;
    if (t < 65536) {
        int e = t & 7, l = (t >> 3) & 63, ks = (t >> 9) & 7, nt = (t >> 12) & 7, br = (t >> 15) & 1;
        int cc = ks * 32 + (l >> 4) * 8 + e;
        int n = nt * 16 + (l & 15);
        const float* W = br ? W1 : W01;
        wpa[t] = f2bf(W[cc * 128 + n]);
    } else {
        int t2 = t - 65536;   // < 16384
        int e = t2 & 7, l = (t2 >> 3) & 63, ks = (t2 >> 9) & 3, nt = (t2 >> 11) & 3, br = (t2 >> 13) & 1;
        int cc = ks * 32 + (l >> 4) * 8 + e;
        int n = nt * 16 + (l & 15);
        const float* W = br ? W2 : W02;
        wpb[t2] = f2bf(W[cc * 64 + n]);
    }
}

// ---------------- Xp = concat(X, X[:,:,:4]) @ Wv + bv + bq + Qp  (MFMA, 8-wave split-K) ----------------
__global__ __launch_bounds__(512) void xp_kernel(
    const float* __restrict__ X, const unsigned short* __restrict__ wvp,
    const float* __restrict__ bv, const float* __restrict__ bq,
    const float* __restrict__ Qpp, float* __restrict__ Xp)
{
    __shared__ f32x4 red[8][4][65];
    const int tid = threadIdx.x;
    const int w = tid >> 6;           // 0..7
    const int lane = tid & 63;
    const int g = lane >> 4, j16 = lane & 15;
    const int mt = blockIdx.x;        // 16-row tile
    const int bn = blockIdx.y;        // 64-col tile
    const int b  = blockIdx.z;

    const int i0 = mt * 16;
    const int n0 = bn * 64;
    const float* xrow = X + ((size_t)(b * NR) + (i0 + j16)) * 2052;

    f32x4 acc[4] = {};

    for (int ks = w; ks < 64; ks += 8) {
        const int c0 = ks * 32 + g * 8;
        float4 xa = *(const float4*)(xrow + c0);
        float4 xb = *(const float4*)(xrow + c0 + 4);
        union { short8 s; unsigned int u[4]; } af;
        af.u[0] = pk2bf(xa.x, xa.y);
        af.u[1] = pk2bf(xa.z, xa.w);
        af.u[2] = pk2bf(xb.x, xb.y);
        af.u[3] = pk2bf(xb.z, xb.w);
        #pragma unroll
        for (int nt = 0; nt < 4; ++nt) {
            short8 bf = ((const short8*)wvp)[(size_t)(ks * 16 + bn * 4 + nt) * 64 + lane];
            acc[nt] = __builtin_amdgcn_mfma_f32_16x16x32_bf16(af.s, bf, acc[nt], 0, 0, 0);
        }
    }
    if (w == 0) {  // ks = 64 tail
        float xv[8];
        #pragma unroll
        for (int e = 0; e < 8; ++e) {
            int q = g * 8 + e;
            int csrc = (q < 4) ? (2048 + q) : (q - 4);
            xv[e] = xrow[csrc];
        }
        union { short8 s; unsigned int u[4]; } af;
        af.u[0] = pk2bf(xv[0], xv[1]);
        af.u[1] = pk2bf(xv[2], xv[3]);
        af.u[2] = pk2bf(xv[4], xv[5]);
        af.u[3] = pk2bf(xv[6], xv[7]);
        #pragma unroll
        for (int nt = 0; nt < 4; ++nt) {
            short8 bf = ((const short8*)wvp)[(size_t)(64 * 16 + bn * 4 + nt) * 64 + lane];
            acc[nt] = __builtin_amdgcn_mfma_f32_16x16x32_bf16(af.s, bf, acc[nt], 0, 0, 0);
        }
    }
    #pragma unroll
    for (int nt = 0; nt < 4; ++nt) red[w][nt][lane] = acc[nt];
    __syncthreads();

    {
        int nt = tid >> 7;
        int l  = tid & 63;
        int half = (tid >> 6) & 1;
        float r0 = 0.f, r1 = 0.f;
        #pragma unroll
        for (int ww = 0; ww < 8; ++ww) {
            f32x4 v = red[ww][nt][l];
            r0 += v[half * 2 + 0];
            r1 += v[half * 2 + 1];
        }
        int gg = l >> 4, jj = l & 15;
        int n = n0 + nt * 16 + jj;
        float base = bv[n] + bq[n] + Qpp[b * 256 + n] + Qpp[(4 + b) * 256 + n]
                   + Qpp[(8 + b) * 256 + n] + Qpp[(12 + b) * 256 + n];
        int row0 = i0 + gg * 4 + half * 2;
        Xp[((b * NR) + row0) * CC + n]       = r0 + base;
        Xp[((b * NR) + row0 + 1) * CC + n]   = r1 + base;
    }
}

// ---------------- fused 3-layer MLP over pairs: 8-wave blocks, upper-tri, swapped MFMA ----------------
// block = (b, it in [0,32), jt in [it/4, 8)): 8 waves, wave = i = it*8+wave, j-tile 32.
__global__ __launch_bounds__(512, 4) void pairs_kernel(
    const float* __restrict__ Xp,
    const unsigned short* __restrict__ wpa,
    const unsigned short* __restrict__ wpb,
    const float* __restrict__ b01, const float* __restrict__ b02,
    const float* __restrict__ W03, const float* __restrict__ b03,
    const float* __restrict__ b1,  const float* __restrict__ b2,
    const float* __restrict__ W3,  const float* __restrict__ b3,
    float* __restrict__ hout)
{
    __shared__ __align__(16) unsigned short lds_wa[32768];   // 64 KB: one branch's L1 weights
    __shared__ __align__(16) float lds_si[2048];             // 8 i-rows of Xp
    __shared__ __align__(16) float lds_bias1[128];
    __shared__ __align__(16) float lds_bias2[64];
    __shared__ __align__(16) float lds_w3[64];
    __shared__ float lds_t[32][9];                           // h tile (j-local x i-local), padded

    const int tid = threadIdx.x;
    const int wave = tid >> 6;
    const int lane = tid & 63;
    const int g = lane >> 4;
    const int j16 = lane & 15;

    // grid decode: bx -> (b, it, jt), 144 tiles per b
    int bx = blockIdx.x;
    int b = bx / 144;
    int u = bx - b * 144;
    int k = 0, off = 0;
    while (u >= off + 4 * (8 - k)) { off += 4 * (8 - k); ++k; }
    int rel = u - off, wdt = 8 - k;
    int it = k * 4 + rel / wdt;
    int jt = k + rel % wdt;

    const int i0 = it * 8;
    const int i = i0 + wave;
    const int j0 = jt * 32;

    // stage the 8 i-rows
    {
        int ww = tid >> 6, c4 = (tid & 63) * 4;
        *(float4*)&lds_si[ww * 256 + c4] =
            *(const float4*)&Xp[((b * NR) + (i0 + ww)) * CC + c4];
    }

    const float* xrow0 = Xp + ((size_t)(b * NR) + (j0 + j16)) * CC;
    const float* xrow1 = Xp + ((size_t)(b * NR) + (j0 + 16 + j16)) * CC;
    const float* si = lds_si + wave * 256;
    const int s0 = ((lane & 16) ? 32 : 0) + j16;
    const int s1 = s0 + 16;
    const bool hi = (g >> 1);

    for (int br = 0; br < 2; ++br) {
        __syncthreads();   // prior-branch LDS reads done (and si/lds_t uses done)
        {
            const uint4* gsrc = (const uint4*)(wpa + br * 32768);
            uint4* sdst = (uint4*)lds_wa;
            #pragma unroll
            for (int kk = 0; kk < 8; ++kk) sdst[kk * 512 + tid] = gsrc[kk * 512 + tid];
            if (tid < 128) lds_bias1[tid] = br ? b1[tid] : b01[tid];
            else if (tid < 192) lds_bias2[tid - 128] = br ? b2[tid - 128] : b02[tid - 128];
            else if (tid < 256) lds_w3[tid - 192] = br ? W3[tid - 192] : W03[tid - 192];
        }
        __syncthreads();
        const float b3v = br ? b3[0] : b03[0];

        // W2^T fragments in registers
        short8 wbf[16];
        #pragma unroll
        for (int q = 0; q < 16; ++q)
            wbf[q] = ((const short8*)wpb)[(br * 16 + q) * 64 + lane];
        f32x4 w3v[4];
        #pragma unroll
        for (int nt2 = 0; nt2 < 4; ++nt2)
            w3v[nt2] = *(const f32x4*)&lds_w3[nt2 * 16 + g * 4];

        #pragma unroll
        for (int mj = 0; mj < 2; ++mj) {
            const float* xr = mj ? xrow1 : xrow0;

            // B-fragments of P^T
            short8 bfr[8];
            #pragma unroll
            for (int ks = 0; ks < 8; ++ks) {
                const int c0 = ks * 32 + g * 8;
                float4 xa = *(const float4*)(xr + c0);
                float4 xb = *(const float4*)(xr + c0 + 4);
                float4 sa = *(const float4*)(si + c0);
                float4 sb = *(const float4*)(si + c0 + 4);
                union { short8 s; unsigned int u[4]; } f;
                f.u[0] = pk2bf(xa.x * sa.x, xa.y * sa.y);
                f.u[1] = pk2bf(xa.z * sa.z, xa.w * sa.w);
                f.u[2] = pk2bf(xb.x * sb.x, xb.y * sb.y);
                f.u[3] = pk2bf(xb.z * sb.z, xb.w * sb.w);
                bfr[ks] = f.s;
            }

            // layer 1 (swapped): C-init = bias1
            f32x4 acc1[8];
            #pragma unroll
            for (int nt1 = 0; nt1 < 8; ++nt1)
                acc1[nt1] = *(const f32x4*)&lds_bias1[nt1 * 16 + g * 4];
            #pragma unroll
            for (int ks = 0; ks < 8; ++ks) {
                #pragma unroll
                for (int nt1 = 0; nt1 < 8; ++nt1) {
                    short8 wf = ((const short8*)lds_wa)[(nt1 * 8 + ks) * 64 + lane];
                    acc1[nt1] = __builtin_amdgcn_mfma_f32_16x16x32_bf16(wf, bfr[ks], acc1[nt1], 0, 0, 0);
                }
            }

            // layer 2 (swapped): relu+pack, shuffle-exchange, 16 MFMAs
            f32x4 acc2[4];
            #pragma unroll
            for (int nt2 = 0; nt2 < 4; ++nt2)
                acc2[nt2] = *(const f32x4*)&lds_bias2[nt2 * 16 + g * 4];
            #pragma unroll
            for (int t = 0; t < 4; ++t) {
                float e0 = fmaxf(acc1[2*t][0], 0.f),   e1 = fmaxf(acc1[2*t][1], 0.f);
                float e2 = fmaxf(acc1[2*t][2], 0.f),   e3 = fmaxf(acc1[2*t][3], 0.f);
                float o0 = fmaxf(acc1[2*t+1][0], 0.f), o1 = fmaxf(acc1[2*t+1][1], 0.f);
                float o2 = fmaxf(acc1[2*t+1][2], 0.f), o3 = fmaxf(acc1[2*t+1][3], 0.f);
                unsigned int uE0 = pk2bf(e0, e1), uE1 = pk2bf(e2, e3);
                unsigned int uO0 = pk2bf(o0, o1), uO1 = pk2bf(o2, o3);
                unsigned int aE0 = __shfl(uE0, s0, 64), aO0 = __shfl(uO0, s0, 64);
                unsigned int aE1 = __shfl(uE1, s0, 64), aO1 = __shfl(uO1, s0, 64);
                unsigned int bE0 = __shfl(uE0, s1, 64), bO0 = __shfl(uO0, s1, 64);
                unsigned int bE1 = __shfl(uE1, s1, 64), bO1 = __shfl(uO1, s1, 64);
                union { short8 s; unsigned int u[4]; } B2;
                B2.u[0] = hi ? aO0 : aE0;
                B2.u[1] = hi ? aO1 : aE1;
                B2.u[2] = hi ? bO0 : bE0;
                B2.u[3] = hi ? bO1 : bE1;
                #pragma unroll
                for (int nt2 = 0; nt2 < 4; ++nt2)
                    acc2[nt2] = __builtin_amdgcn_mfma_f32_16x16x32_bf16(wbf[nt2 * 4 + t], B2.s, acc2[nt2], 0, 0, 0);
            }

            // layer 3
            float part = 0.f;
            #pragma unroll
            for (int nt2 = 0; nt2 < 4; ++nt2) {
                part += fmaxf(acc2[nt2][0], 0.f) * w3v[nt2][0];
                part += fmaxf(acc2[nt2][1], 0.f) * w3v[nt2][1];
                part += fmaxf(acc2[nt2][2], 0.f) * w3v[nt2][2];
                part += fmaxf(acc2[nt2][3], 0.f) * w3v[nt2][3];
            }
            part += __shfl_xor(part, 16, 64);
            part += __shfl_xor(part, 32, 64);
            float h3 = part + b3v;
            h3 = h3 > 0.f ? h3 : 0.f;

            if (g == 0) lds_t[mj * 16 + j16][wave] = h3;
        }

        // cooperative coalesced write of upper + mirror tiles
        __syncthreads();
        {
            float* hb = hout + ((size_t)(br * 4 + b) << 16);
            if (tid < 256) {           // upper: 8 rows x 32 cols (128B rows)
                int ii = tid >> 5, jj = tid & 31;
                int irow = i0 + ii, jcol = j0 + jj;
                if (jcol >= irow) hb[irow * NR + jcol] = lds_t[jj][ii];
            } else {                   // mirror: 32 rows x 8 cols (32B rows)
                int t2 = tid - 256;
                int jj = t2 >> 3, ii = t2 & 7;
                int irow = i0 + ii, jcol = j0 + jj;
                if (jcol > irow) hb[jcol * NR + irow] = lds_t[jj][ii];
            }
        }
    }
}

// ---------------- colsoft stage 1: partial column sums of exp(2h) ----------------
__global__ __launch_bounds__(256) void colsoft_part_kernel(
    const float* __restrict__ h, float* __restrict__ cpart)
{
    const int blk = blockIdx.x;        // 0..7 = br*4+b
    const int ic  = blockIdx.y;        // 0..7 i-chunk
    const int j = threadIdx.x;
    const float* hb = h + ((size_t)blk << 16) + (size_t)ic * 32 * NR;
    float cs = 0.f;
    #pragma unroll 4
    for (int r = 0; r < 32; ++r) cs += __expf(2.f * hb[r * NR + j]);
    cpart[(blk * 8 + ic) * 256 + j] = cs;
}

// ---------------- colsoft stage 2: reduce partials, normalize ----------------
__global__ __launch_bounds__(256) void colsoft_final_kernel(
    const float* __restrict__ cpart, float* __restrict__ wn)
{
    const int blk = blockIdx.x;
    const int j = threadIdx.x;
    float cs = 0.f;
    #pragma unroll
    for (int ic = 0; ic < 8; ++ic) cs += cpart[(blk * 8 + ic) * 256 + j];
    __shared__ float red[256];
    red[j] = cs; __syncthreads();
    for (int s = 128; s > 0; s >>= 1) {
        if (j < s) red[j] += red[j + s];
        __syncthreads();
    }
    wn[blk * 256 + j] = cs / red[0];
}

// ---------------- agg stage 1: partial weighted sums over j-chunks ----------------
__global__ __launch_bounds__(256) void agg_part_kernel(
    const float* __restrict__ X, const float* __restrict__ wn,
    float* __restrict__ apart)
{
    const int dc = blockIdx.x, b = blockIdx.y, jc = blockIdx.z;
    const int d = dc * 256 + threadIdx.x;
    __shared__ float wc[32];
    if (threadIdx.x < 32) {
        int j = jc * 32 + threadIdx.x;
        wc[threadIdx.x] = 0.5f * (wn[b * 256 + j] + wn[(4 + b) * 256 + j]);
    }
    __syncthreads();
    if (d < 2052) {
        const float* xp = X + (size_t)b * NR * 2052 + (size_t)jc * 32 * 2052 + d;
        float a0 = 0.f, a1 = 0.f, a2 = 0.f, a3 = 0.f;
        for (int r = 0; r < 32; r += 4) {
            a0 += wc[r + 0] * xp[(size_t)(r + 0) * 2052];
            a1 += wc[r + 1] * xp[(size_t)(r + 1) * 2052];
            a2 += wc[r + 2] * xp[(size_t)(r + 2) * 2052];
            a3 += wc[r + 3] * xp[(size_t)(r + 3) * 2052];
        }
        apart[(size_t)(jc * 4 + b) * 2304 + d] = (a0 + a1) + (a2 + a3);
    }
}

// ---------------- agg stage 2: sum partials ----------------
__global__ __launch_bounds__(256) void agg_final_kernel(
    const float* __restrict__ apart, float* __restrict__ out)
{
    const int dc = blockIdx.x, b = blockIdx.y;
    const int d = dc * 256 + threadIdx.x;
    if (d < 2052) {
        float s = 0.f;
        #pragma unroll
        for (int jc = 0; jc < 8; ++jc) s += apart[(size_t)(jc * 4 + b) * 2304 + d];
        out[b * 2052 + d] = s;
    }
}

extern "C" void kernel_launch(void* const* d_in, const int* in_sizes, int n_in,
                              void* d_out, int out_size, void* d_ws, size_t ws_size,
                              hipStream_t stream) {
    const float* Q   = (const float*)d_in[0];
    const float* X   = (const float*)d_in[1];
    const float* Wv  = (const float*)d_in[2];
    const float* bv  = (const float*)d_in[3];
    const float* Wq  = (const float*)d_in[4];
    const float* bq  = (const float*)d_in[5];
    const float* W01 = (const float*)d_in[6];
    const float* b01 = (const float*)d_in[7];
    const float* W02 = (const float*)d_in[8];
    const float* b02 = (const float*)d_in[9];
    const float* W03 = (const float*)d_in[10];
    const float* b03 = (const float*)d_in[11];
    const float* W1  = (const float*)d_in[12];
    const float* b1  = (const float*)d_in[13];
    const float* W2  = (const float*)d_in[14];
    const float* b2  = (const float*)d_in[15];
    const float* W3  = (const float*)d_in[16];
    const float* b3  = (const float*)d_in[17];

    char* ws = (char*)d_ws;
    // layout; aliases: wvp over hbuf (dead before pairs), cpart over wpa (dead
    // after pairs), apart over Xp (dead after pairs)
    float* Xp   = (float*)(ws + 0);              // 1,048,576 B
    float* Qpp  = (float*)(ws + 1048576);        //    16,384 B
    float* wn   = (float*)(ws + 1064960);        //     8,192 B
    unsigned short* wpa = (unsigned short*)(ws + 1073152);  // 131,072 B
    unsigned short* wpb = (unsigned short*)(ws + 1204224);  //  32,768 B
    float* hbuf = (float*)(ws + 1236992);        // 2,097,152 B -> end 3,334,144
    unsigned short* wvp = (unsigned short*)(ws + 1236992);  // aliased
    float* cpart = (float*)(ws + 1073152);       // 65,536 B (aliases wpa)
    float* apart = (float*)(ws + 0);             // 294,912 B (aliases Xp)
    float* out = (float*)d_out;

    qp_kernel<<<dim3(4, 4), 256, 0, stream>>>(Q, Wq, Qpp);
    wvp_pack_kernel<<<65, 256, 0, stream>>>(Wv, wvp);
    pack_kernel<<<320, 256, 0, stream>>>(W01, W1, W02, W2, wpa, wpb);
    xp_kernel<<<dim3(16, 4, 4), 512, 0, stream>>>(X, wvp, bv, bq, Qpp, Xp);
    pairs_kernel<<<576, 512, 0, stream>>>(Xp, wpa, wpb, b01, b02, W03, b03,
                                          b1, b2, W3, b3, hbuf);
    colsoft_part_kernel<<<dim3(8, 8), 256, 0, stream>>>(hbuf, cpart);
    colsoft_final_kernel<<<8, 256, 0, stream>>>(cpart, wn);
    agg_part_kernel<<<dim3(9, 4, 8), 256, 0, stream>>>(X, wn, apart);
    agg_final_kernel<<<dim3(9, 4), 256, 0, stream>>>(apart, out);
}

// Round 4
// 137.439 us; speedup vs baseline: 1.2968x; 1.2968x over previous
//
#include <hip/hip_runtime.h>
#include <hip/hip_bf16.h>

typedef __attribute__((ext_vector_type(8))) short short8;
typedef __attribute__((ext_vector_type(4))) float f32x4;

#define NR 256
#define CC 256

__device__ __forceinline__ unsigned short f2bf(float x) {
    union { float f; unsigned int u; } v; v.f = x;
    unsigned int r = v.u + 0x7FFFu + ((v.u >> 16) & 1u);
    return (unsigned short)(r >> 16);
}

__device__ __forceinline__ unsigned int pk2bf(float a, float b) {
    __hip_bfloat162 h = __float22bfloat162_rn(make_float2(a, b));
    union { __hip_bfloat162 h; unsigned int u; } cv; cv.h = h;
    return cv.u;
}

// ---------------- Qpp[ksl][b][n] = partial Q @ Wq ----------------
__global__ __launch_bounds__(256) void qp_kernel(
    const float* __restrict__ Q, const float* __restrict__ Wq,
    float* __restrict__ Qpp)
{
    const int ksl = blockIdx.x, b = blockIdx.y;
    const int n = threadIdx.x;
    __shared__ float qs[256];
    qs[n] = Q[b * 1024 + ksl * 256 + n];
    __syncthreads();
    float acc = 0.f;
    #pragma unroll 4
    for (int d = 0; d < 256; ++d) acc += qs[d] * Wq[(size_t)(ksl * 256 + d) * 256 + n];
    Qpp[(ksl * 4 + b) * 256 + n] = acc;
}

// ---------------- pack Wv into MFMA B-frag layout (bf16), K padded to 2080 ----------------
__global__ __launch_bounds__(256) void wvp_pack_kernel(
    const float* __restrict__ Wv, unsigned short* __restrict__ wvp)
{
    __shared__ float tile[32][260];
    const int ks = blockIdx.x;   // 0..64
    const int tid = threadIdx.x;
    for (int idx = tid; idx < 32 * 256; idx += 256) {
        int cr = idx >> 8, n = idx & 255;
        int c = ks * 32 + cr;
        tile[cr][n] = (c < 2056) ? Wv[(size_t)c * 256 + n] : 0.f;
    }
    __syncthreads();
    #pragma unroll
    for (int q = 0; q < 4; ++q) {
        int t2 = tid * 4 + q;
        int nt = t2 >> 6, l = t2 & 63;
        int gg = l >> 4, jj = l & 15;
        short8 s;
        #pragma unroll
        for (int e = 0; e < 8; ++e)
            s[e] = (short)f2bf(tile[gg * 8 + e][nt * 16 + jj]);
        *(short8*)&wvp[((size_t)(ks * 16 + nt) * 64 + l) * 8] = s;
    }
}

// ---------------- pack MLP weights into MFMA fragment layout (bf16) ----------------
__global__ __launch_bounds__(256) void pack_kernel(
    const float* __restrict__ W01, const float* __restrict__ W1,
    const float* __restrict__ W02, const float* __restrict__ W2,
    unsigned short* __restrict__ wpa, unsigned short* __restrict__ wpb)
{
    int t = blockIdx.x * 256 + threadIdx.x;
    if (t < 65536) {
        int e = t & 7, l = (t >> 3) & 63, ks = (t >> 9) & 7, nt = (t >> 12) & 7, br = (t >> 15) & 1;
        int cc = ks * 32 + (l >> 4) * 8 + e;
        int n = nt * 16 + (l & 15);
        const float* W = br ? W1 : W01;
        wpa[t] = f2bf(W[cc * 128 + n]);
    } else {
        int t2 = t - 65536;   // < 16384
        int e = t2 & 7, l = (t2 >> 3) & 63, ks = (t2 >> 9) & 3, nt = (t2 >> 11) & 3, br = (t2 >> 13) & 1;
        int cc = ks * 32 + (l >> 4) * 8 + e;
        int n = nt * 16 + (l & 15);
        const float* W = br ? W2 : W02;
        wpb[t2] = f2bf(W[cc * 64 + n]);
    }
}

// ---------------- Xp = concat(X, X[:,:,:4]) @ Wv + bv + bq + Qp  (MFMA, 8-wave split-K) ----------------
__global__ __launch_bounds__(512) void xp_kernel(
    const float* __restrict__ X, const unsigned short* __restrict__ wvp,
    const float* __restrict__ bv, const float* __restrict__ bq,
    const float* __restrict__ Qpp, float* __restrict__ Xp)
{
    __shared__ f32x4 red[8][4][65];
    const int tid = threadIdx.x;
    const int w = tid >> 6;           // 0..7
    const int lane = tid & 63;
    const int g = lane >> 4, j16 = lane & 15;
    const int mt = blockIdx.x;        // 16-row tile
    const int bn = blockIdx.y;        // 64-col tile
    const int b  = blockIdx.z;

    const int i0 = mt * 16;
    const int n0 = bn * 64;
    const float* xrow = X + ((size_t)(b * NR) + (i0 + j16)) * 2052;

    f32x4 acc[4] = {};

    for (int ks = w; ks < 64; ks += 8) {
        const int c0 = ks * 32 + g * 8;
        float4 xa = *(const float4*)(xrow + c0);
        float4 xb = *(const float4*)(xrow + c0 + 4);
        union { short8 s; unsigned int u[4]; } af;
        af.u[0] = pk2bf(xa.x, xa.y);
        af.u[1] = pk2bf(xa.z, xa.w);
        af.u[2] = pk2bf(xb.x, xb.y);
        af.u[3] = pk2bf(xb.z, xb.w);
        #pragma unroll
        for (int nt = 0; nt < 4; ++nt) {
            short8 bf = ((const short8*)wvp)[(size_t)(ks * 16 + bn * 4 + nt) * 64 + lane];
            acc[nt] = __builtin_amdgcn_mfma_f32_16x16x32_bf16(af.s, bf, acc[nt], 0, 0, 0);
        }
    }
    if (w == 0) {  // ks = 64 tail
        float xv[8];
        #pragma unroll
        for (int e = 0; e < 8; ++e) {
            int q = g * 8 + e;
            int csrc = (q < 4) ? (2048 + q) : (q - 4);
            xv[e] = xrow[csrc];
        }
        union { short8 s; unsigned int u[4]; } af;
        af.u[0] = pk2bf(xv[0], xv[1]);
        af.u[1] = pk2bf(xv[2], xv[3]);
        af.u[2] = pk2bf(xv[4], xv[5]);
        af.u[3] = pk2bf(xv[6], xv[7]);
        #pragma unroll
        for (int nt = 0; nt < 4; ++nt) {
            short8 bf = ((const short8*)wvp)[(size_t)(64 * 16 + bn * 4 + nt) * 64 + lane];
            acc[nt] = __builtin_amdgcn_mfma_f32_16x16x32_bf16(af.s, bf, acc[nt], 0, 0, 0);
        }
    }
    #pragma unroll
    for (int nt = 0; nt < 4; ++nt) red[w][nt][lane] = acc[nt];
    __syncthreads();

    {
        int nt = tid >> 7;
        int l  = tid & 63;
        int half = (tid >> 6) & 1;
        float r0 = 0.f, r1 = 0.f;
        #pragma unroll
        for (int ww = 0; ww < 8; ++ww) {
            f32x4 v = red[ww][nt][l];
            r0 += v[half * 2 + 0];
            r1 += v[half * 2 + 1];
        }
        int gg = l >> 4, jj = l & 15;
        int n = n0 + nt * 16 + jj;
        float base = bv[n] + bq[n] + Qpp[b * 256 + n] + Qpp[(4 + b) * 256 + n]
                   + Qpp[(8 + b) * 256 + n] + Qpp[(12 + b) * 256 + n];
        int row0 = i0 + gg * 4 + half * 2;
        Xp[((b * NR) + row0) * CC + n]       = r0 + base;
        Xp[((b * NR) + row0 + 1) * CC + n]   = r1 + base;
    }
}

// ---------------- fused 3-layer MLP over pairs: 8-wave blocks, upper-tri, swapped MFMA ----------------
// block = (b, it in [0,32), jt in [it/4, 8)): 8 waves, wave = i = it*8+wave, j-tile 32.
// __launch_bounds__(512, 2): 2nd arg MUST NOT push VGPR cap below 128 —
// (512,4) pinned VGPR=64 and spilled ~400MB/dispatch to scratch (round-3 regression).
__global__ __launch_bounds__(512, 2) void pairs_kernel(
    const float* __restrict__ Xp,
    const unsigned short* __restrict__ wpa,
    const unsigned short* __restrict__ wpb,
    const float* __restrict__ b01, const float* __restrict__ b02,
    const float* __restrict__ W03, const float* __restrict__ b03,
    const float* __restrict__ b1,  const float* __restrict__ b2,
    const float* __restrict__ W3,  const float* __restrict__ b3,
    float* __restrict__ hout)
{
    __shared__ __align__(16) unsigned short lds_wa[32768];   // 64 KB: one branch's L1 weights
    __shared__ __align__(16) float lds_si[2048];             // 8 i-rows of Xp
    __shared__ __align__(16) float lds_bias1[128];
    __shared__ __align__(16) float lds_bias2[64];
    __shared__ __align__(16) float lds_w3[64];
    __shared__ float lds_t[32][9];                           // h tile (j-local x i-local), padded

    const int tid = threadIdx.x;
    const int wave = tid >> 6;
    const int lane = tid & 63;
    const int g = lane >> 4;
    const int j16 = lane & 15;

    // grid decode: bx -> (b, it, jt), 144 tiles per b
    int bx = blockIdx.x;
    int b = bx / 144;
    int u = bx - b * 144;
    int k = 0, off = 0;
    while (u >= off + 4 * (8 - k)) { off += 4 * (8 - k); ++k; }
    int rel = u - off, wdt = 8 - k;
    int it = k * 4 + rel / wdt;
    int jt = k + rel % wdt;

    const int i0 = it * 8;
    const int i = i0 + wave;
    const int j0 = jt * 32;

    // stage the 8 i-rows
    {
        int ww = tid >> 6, c4 = (tid & 63) * 4;
        *(float4*)&lds_si[ww * 256 + c4] =
            *(const float4*)&Xp[((b * NR) + (i0 + ww)) * CC + c4];
    }

    const float* xrow0 = Xp + ((size_t)(b * NR) + (j0 + j16)) * CC;
    const float* xrow1 = Xp + ((size_t)(b * NR) + (j0 + 16 + j16)) * CC;
    const float* si = lds_si + wave * 256;
    const int s0 = ((lane & 16) ? 32 : 0) + j16;
    const int s1 = s0 + 16;
    const bool hi = (g >> 1);

    for (int br = 0; br < 2; ++br) {
        __syncthreads();   // prior-branch LDS reads done (and si/lds_t uses done)
        {
            const uint4* gsrc = (const uint4*)(wpa + br * 32768);
            uint4* sdst = (uint4*)lds_wa;
            #pragma unroll
            for (int kk = 0; kk < 8; ++kk) sdst[kk * 512 + tid] = gsrc[kk * 512 + tid];
            if (tid < 128) lds_bias1[tid] = br ? b1[tid] : b01[tid];
            else if (tid < 192) lds_bias2[tid - 128] = br ? b2[tid - 128] : b02[tid - 128];
            else if (tid < 256) lds_w3[tid - 192] = br ? W3[tid - 192] : W03[tid - 192];
        }
        __syncthreads();
        const float b3v = br ? b3[0] : b03[0];

        // W2^T fragments in registers
        short8 wbf[16];
        #pragma unroll
        for (int q = 0; q < 16; ++q)
            wbf[q] = ((const short8*)wpb)[(br * 16 + q) * 64 + lane];
        f32x4 w3v[4];
        #pragma unroll
        for (int nt2 = 0; nt2 < 4; ++nt2)
            w3v[nt2] = *(const f32x4*)&lds_w3[nt2 * 16 + g * 4];

        #pragma unroll
        for (int mj = 0; mj < 2; ++mj) {
            const float* xr = mj ? xrow1 : xrow0;

            // B-fragments of P^T
            short8 bfr[8];
            #pragma unroll
            for (int ks = 0; ks < 8; ++ks) {
                const int c0 = ks * 32 + g * 8;
                float4 xa = *(const float4*)(xr + c0);
                float4 xb = *(const float4*)(xr + c0 + 4);
                float4 sa = *(const float4*)(si + c0);
                float4 sb = *(const float4*)(si + c0 + 4);
                union { short8 s; unsigned int u[4]; } f;
                f.u[0] = pk2bf(xa.x * sa.x, xa.y * sa.y);
                f.u[1] = pk2bf(xa.z * sa.z, xa.w * sa.w);
                f.u[2] = pk2bf(xb.x * sb.x, xb.y * sb.y);
                f.u[3] = pk2bf(xb.z * sb.z, xb.w * sb.w);
                bfr[ks] = f.s;
            }

            // layer 1 (swapped): C-init = bias1
            f32x4 acc1[8];
            #pragma unroll
            for (int nt1 = 0; nt1 < 8; ++nt1)
                acc1[nt1] = *(const f32x4*)&lds_bias1[nt1 * 16 + g * 4];
            #pragma unroll
            for (int ks = 0; ks < 8; ++ks) {
                #pragma unroll
                for (int nt1 = 0; nt1 < 8; ++nt1) {
                    short8 wf = ((const short8*)lds_wa)[(nt1 * 8 + ks) * 64 + lane];
                    acc1[nt1] = __builtin_amdgcn_mfma_f32_16x16x32_bf16(wf, bfr[ks], acc1[nt1], 0, 0, 0);
                }
            }

            // layer 2 (swapped): relu+pack, shuffle-exchange, 16 MFMAs
            f32x4 acc2[4];
            #pragma unroll
            for (int nt2 = 0; nt2 < 4; ++nt2)
                acc2[nt2] = *(const f32x4*)&lds_bias2[nt2 * 16 + g * 4];
            #pragma unroll
            for (int t = 0; t < 4; ++t) {
                float e0 = fmaxf(acc1[2*t][0], 0.f),   e1 = fmaxf(acc1[2*t][1], 0.f);
                float e2 = fmaxf(acc1[2*t][2], 0.f),   e3 = fmaxf(acc1[2*t][3], 0.f);
                float o0 = fmaxf(acc1[2*t+1][0], 0.f), o1 = fmaxf(acc1[2*t+1][1], 0.f);
                float o2 = fmaxf(acc1[2*t+1][2], 0.f), o3 = fmaxf(acc1[2*t+1][3], 0.f);
                unsigned int uE0 = pk2bf(e0, e1), uE1 = pk2bf(e2, e3);
                unsigned int uO0 = pk2bf(o0, o1), uO1 = pk2bf(o2, o3);
                unsigned int aE0 = __shfl(uE0, s0, 64), aO0 = __shfl(uO0, s0, 64);
                unsigned int aE1 = __shfl(uE1, s0, 64), aO1 = __shfl(uO1, s0, 64);
                unsigned int bE0 = __shfl(uE0, s1, 64), bO0 = __shfl(uO0, s1, 64);
                unsigned int bE1 = __shfl(uE1, s1, 64), bO1 = __shfl(uO1, s1, 64);
                union { short8 s; unsigned int u[4]; } B2;
                B2.u[0] = hi ? aO0 : aE0;
                B2.u[1] = hi ? aO1 : aE1;
                B2.u[2] = hi ? bO0 : bE0;
                B2.u[3] = hi ? bO1 : bE1;
                #pragma unroll
                for (int nt2 = 0; nt2 < 4; ++nt2)
                    acc2[nt2] = __builtin_amdgcn_mfma_f32_16x16x32_bf16(wbf[nt2 * 4 + t], B2.s, acc2[nt2], 0, 0, 0);
            }

            // layer 3
            float part = 0.f;
            #pragma unroll
            for (int nt2 = 0; nt2 < 4; ++nt2) {
                part += fmaxf(acc2[nt2][0], 0.f) * w3v[nt2][0];
                part += fmaxf(acc2[nt2][1], 0.f) * w3v[nt2][1];
                part += fmaxf(acc2[nt2][2], 0.f) * w3v[nt2][2];
                part += fmaxf(acc2[nt2][3], 0.f) * w3v[nt2][3];
            }
            part += __shfl_xor(part, 16, 64);
            part += __shfl_xor(part, 32, 64);
            float h3 = part + b3v;
            h3 = h3 > 0.f ? h3 : 0.f;

            if (g == 0) lds_t[mj * 16 + j16][wave] = h3;
        }

        // cooperative coalesced write of upper + mirror tiles
        __syncthreads();
        {
            float* hb = hout + ((size_t)(br * 4 + b) << 16);
            if (tid < 256) {           // upper: 8 rows x 32 cols (128B rows)
                int ii = tid >> 5, jj = tid & 31;
                int irow = i0 + ii, jcol = j0 + jj;
                if (jcol >= irow) hb[irow * NR + jcol] = lds_t[jj][ii];
            } else {                   // mirror: 32 rows x 8 cols (32B rows)
                int t2 = tid - 256;
                int jj = t2 >> 3, ii = t2 & 7;
                int irow = i0 + ii, jcol = j0 + jj;
                if (jcol > irow) hb[jcol * NR + irow] = lds_t[jj][ii];
            }
        }
    }
}

// ---------------- colsoft stage 1: partial column sums of exp(2h) ----------------
__global__ __launch_bounds__(256) void colsoft_part_kernel(
    const float* __restrict__ h, float* __restrict__ cpart)
{
    const int blk = blockIdx.x;        // 0..7 = br*4+b
    const int ic  = blockIdx.y;        // 0..7 i-chunk
    const int j = threadIdx.x;
    const float* hb = h + ((size_t)blk << 16) + (size_t)ic * 32 * NR;
    float cs = 0.f;
    #pragma unroll 4
    for (int r = 0; r < 32; ++r) cs += __expf(2.f * hb[r * NR + j]);
    cpart[(blk * 8 + ic) * 256 + j] = cs;
}

// ---------------- colsoft stage 2: reduce partials, normalize ----------------
__global__ __launch_bounds__(256) void colsoft_final_kernel(
    const float* __restrict__ cpart, float* __restrict__ wn)
{
    const int blk = blockIdx.x;
    const int j = threadIdx.x;
    float cs = 0.f;
    #pragma unroll
    for (int ic = 0; ic < 8; ++ic) cs += cpart[(blk * 8 + ic) * 256 + j];
    __shared__ float red[256];
    red[j] = cs; __syncthreads();
    for (int s = 128; s > 0; s >>= 1) {
        if (j < s) red[j] += red[j + s];
        __syncthreads();
    }
    wn[blk * 256 + j] = cs / red[0];
}

// ---------------- agg stage 1: partial weighted sums over j-chunks ----------------
__global__ __launch_bounds__(256) void agg_part_kernel(
    const float* __restrict__ X, const float* __restrict__ wn,
    float* __restrict__ apart)
{
    const int dc = blockIdx.x, b = blockIdx.y, jc = blockIdx.z;
    const int d = dc * 256 + threadIdx.x;
    __shared__ float wc[32];
    if (threadIdx.x < 32) {
        int j = jc * 32 + threadIdx.x;
        wc[threadIdx.x] = 0.5f * (wn[b * 256 + j] + wn[(4 + b) * 256 + j]);
    }
    __syncthreads();
    if (d < 2052) {
        const float* xp = X + (size_t)b * NR * 2052 + (size_t)jc * 32 * 2052 + d;
        float a0 = 0.f, a1 = 0.f, a2 = 0.f, a3 = 0.f;
        for (int r = 0; r < 32; r += 4) {
            a0 += wc[r + 0] * xp[(size_t)(r + 0) * 2052];
            a1 += wc[r + 1] * xp[(size_t)(r + 1) * 2052];
            a2 += wc[r + 2] * xp[(size_t)(r + 2) * 2052];
            a3 += wc[r + 3] * xp[(size_t)(r + 3) * 2052];
        }
        apart[(size_t)(jc * 4 + b) * 2304 + d] = (a0 + a1) + (a2 + a3);
    }
}

// ---------------- agg stage 2: sum partials ----------------
__global__ __launch_bounds__(256) void agg_final_kernel(
    const float* __restrict__ apart, float* __restrict__ out)
{
    const int dc = blockIdx.x, b = blockIdx.y;
    const int d = dc * 256 + threadIdx.x;
    if (d < 2052) {
        float s = 0.f;
        #pragma unroll
        for (int jc = 0; jc < 8; ++jc) s += apart[(size_t)(jc * 4 + b) * 2304 + d];
        out[b * 2052 + d] = s;
    }
}

extern "C" void kernel_launch(void* const* d_in, const int* in_sizes, int n_in,
                              void* d_out, int out_size, void* d_ws, size_t ws_size,
                              hipStream_t stream) {
    const float* Q   = (const float*)d_in[0];
    const float* X   = (const float*)d_in[1];
    const float* Wv  = (const float*)d_in[2];
    const float* bv  = (const float*)d_in[3];
    const float* Wq  = (const float*)d_in[4];
    const float* bq  = (const float*)d_in[5];
    const float* W01 = (const float*)d_in[6];
    const float* b01 = (const float*)d_in[7];
    const float* W02 = (const float*)d_in[8];
    const float* b02 = (const float*)d_in[9];
    const float* W03 = (const float*)d_in[10];
    const float* b03 = (const float*)d_in[11];
    const float* W1  = (const float*)d_in[12];
    const float* b1  = (const float*)d_in[13];
    const float* W2  = (const float*)d_in[14];
    const float* b2  = (const float*)d_in[15];
    const float* W3  = (const float*)d_in[16];
    const float* b3  = (const float*)d_in[17];

    char* ws = (char*)d_ws;
    // layout; aliases: wvp over hbuf (dead before pairs), cpart over wpa (dead
    // after pairs), apart over Xp (dead after pairs)
    float* Xp   = (float*)(ws + 0);              // 1,048,576 B
    float* Qpp  = (float*)(ws + 1048576);        //    16,384 B
    float* wn   = (float*)(ws + 1064960);        //     8,192 B
    unsigned short* wpa = (unsigned short*)(ws + 1073152);  // 131,072 B
    unsigned short* wpb = (unsigned short*)(ws + 1204224);  //  32,768 B
    float* hbuf = (float*)(ws + 1236992);        // 2,097,152 B -> end 3,334,144
    unsigned short* wvp = (unsigned short*)(ws + 1236992);  // aliased
    float* cpart = (float*)(ws + 1073152);       // 65,536 B (aliases wpa)
    float* apart = (float*)(ws + 0);             // 294,912 B (aliases Xp)
    float* out = (float*)d_out;

    qp_kernel<<<dim3(4, 4), 256, 0, stream>>>(Q, Wq, Qpp);
    wvp_pack_kernel<<<65, 256, 0, stream>>>(Wv, wvp);
    pack_kernel<<<320, 256, 0, stream>>>(W01, W1, W02, W2, wpa, wpb);
    xp_kernel<<<dim3(16, 4, 4), 512, 0, stream>>>(X, wvp, bv, bq, Qpp, Xp);
    pairs_kernel<<<576, 512, 0, stream>>>(Xp, wpa, wpb, b01, b02, W03, b03,
                                          b1, b2, W3, b3, hbuf);
    colsoft_part_kernel<<<dim3(8, 8), 256, 0, stream>>>(hbuf, cpart);
    colsoft_final_kernel<<<8, 256, 0, stream>>>(cpart, wn);
    agg_part_kernel<<<dim3(9, 4, 8), 256, 0, stream>>>(X, wn, apart);
    agg_final_kernel<<<dim3(9, 4), 256, 0, stream>>>(apart, out);
}

// Round 5
// 111.939 us; speedup vs baseline: 1.5922x; 1.2278x over previous
//
#include <hip/hip_runtime.h>
#include <hip/hip_bf16.h>

typedef __attribute__((ext_vector_type(8)))  short short8;
typedef __attribute__((ext_vector_type(4)))  float f32x4;
typedef __attribute__((ext_vector_type(16))) float f32x16;

#define NR 256
#define CC 256

__device__ __forceinline__ unsigned short f2bf(float x) {
    union { float f; unsigned int u; } v; v.f = x;
    unsigned int r = v.u + 0x7FFFu + ((v.u >> 16) & 1u);
    return (unsigned short)(r >> 16);
}

__device__ __forceinline__ unsigned int pk2bf(float a, float b) {
    __hip_bfloat162 h = __float22bfloat162_rn(make_float2(a, b));
    union { __hip_bfloat162 h; unsigned int u; } cv; cv.h = h;
    return cv.u;
}

// ---------------- Qpp[ksl][b][n] = partial Q @ Wq ----------------
__global__ __launch_bounds__(256) void qp_kernel(
    const float* __restrict__ Q, const float* __restrict__ Wq,
    float* __restrict__ Qpp)
{
    const int ksl = blockIdx.x, b = blockIdx.y;
    const int n = threadIdx.x;
    __shared__ float qs[256];
    qs[n] = Q[b * 1024 + ksl * 256 + n];
    __syncthreads();
    float acc = 0.f;
    #pragma unroll 4
    for (int d = 0; d < 256; ++d) acc += qs[d] * Wq[(size_t)(ksl * 256 + d) * 256 + n];
    Qpp[(ksl * 4 + b) * 256 + n] = acc;
}

// ---------------- pack Wv into 16x16x32 MFMA B-frag layout (bf16), K padded to 2080 ----------------
__global__ __launch_bounds__(256) void wvp_pack_kernel(
    const float* __restrict__ Wv, unsigned short* __restrict__ wvp)
{
    __shared__ float tile[32][260];
    const int ks = blockIdx.x;   // 0..64
    const int tid = threadIdx.x;
    for (int idx = tid; idx < 32 * 256; idx += 256) {
        int cr = idx >> 8, n = idx & 255;
        int c = ks * 32 + cr;
        tile[cr][n] = (c < 2056) ? Wv[(size_t)c * 256 + n] : 0.f;
    }
    __syncthreads();
    #pragma unroll
    for (int q = 0; q < 4; ++q) {
        int t2 = tid * 4 + q;
        int nt = t2 >> 6, l = t2 & 63;
        int gg = l >> 4, jj = l & 15;
        short8 s;
        #pragma unroll
        for (int e = 0; e < 8; ++e)
            s[e] = (short)f2bf(tile[gg * 8 + e][nt * 16 + jj]);
        *(short8*)&wvp[((size_t)(ks * 16 + nt) * 64 + l) * 8] = s;
    }
}

// ---------------- pack MLP weights into 32x32x16 MFMA A-frag layout (bf16) ----------------
// wpa: [br][nt1(4)][ks(16)][lane(64)][e(8)]  = W[c=16ks+8*(l>>5)+e][n1=32nt1+(l&31)]
// wpb: [br][nt2(2)][ks2(8)][lane(64)][e(8)]  = W2[c=16ks2+8*(l>>5)+e][n2=32nt2+(l&31)]
__global__ __launch_bounds__(256) void pack_kernel(
    const float* __restrict__ W01, const float* __restrict__ W1,
    const float* __restrict__ W02, const float* __restrict__ W2,
    unsigned short* __restrict__ wpa, unsigned short* __restrict__ wpb)
{
    int t = blockIdx.x * 256 + threadIdx.x;
    if (t < 65536) {
        int e = t & 7, l = (t >> 3) & 63, ks = (t >> 9) & 15, nt = (t >> 13) & 3, br = (t >> 15) & 1;
        int cc = ks * 16 + (l >> 5) * 8 + e;
        int n = nt * 32 + (l & 31);
        const float* W = br ? W1 : W01;
        wpa[t] = f2bf(W[cc * 128 + n]);
    } else {
        int t2 = t - 65536;   // < 16384
        int e = t2 & 7, l = (t2 >> 3) & 63, ks = (t2 >> 9) & 7, nt = (t2 >> 12) & 1, br = (t2 >> 13) & 1;
        int cc = ks * 16 + (l >> 5) * 8 + e;
        int n = nt * 32 + (l & 31);
        const float* W = br ? W2 : W02;
        wpb[t2] = f2bf(W[cc * 64 + n]);
    }
}

// ---------------- Xp = concat(X, X[:,:,:4]) @ Wv + bv + bq + Qp  (MFMA, 8-wave split-K) ----------------
__global__ __launch_bounds__(512) void xp_kernel(
    const float* __restrict__ X, const unsigned short* __restrict__ wvp,
    const float* __restrict__ bv, const float* __restrict__ bq,
    const float* __restrict__ Qpp, float* __restrict__ Xp)
{
    __shared__ f32x4 red[8][4][65];
    const int tid = threadIdx.x;
    const int w = tid >> 6;           // 0..7
    const int lane = tid & 63;
    const int g = lane >> 4, j16 = lane & 15;
    const int mt = blockIdx.x;        // 16-row tile
    const int bn = blockIdx.y;        // 64-col tile
    const int b  = blockIdx.z;

    const int i0 = mt * 16;
    const int n0 = bn * 64;
    const float* xrow = X + ((size_t)(b * NR) + (i0 + j16)) * 2052;

    f32x4 acc[4] = {};

    for (int ks = w; ks < 64; ks += 8) {
        const int c0 = ks * 32 + g * 8;
        float4 xa = *(const float4*)(xrow + c0);
        float4 xb = *(const float4*)(xrow + c0 + 4);
        union { short8 s; unsigned int u[4]; } af;
        af.u[0] = pk2bf(xa.x, xa.y);
        af.u[1] = pk2bf(xa.z, xa.w);
        af.u[2] = pk2bf(xb.x, xb.y);
        af.u[3] = pk2bf(xb.z, xb.w);
        #pragma unroll
        for (int nt = 0; nt < 4; ++nt) {
            short8 bf = ((const short8*)wvp)[(size_t)(ks * 16 + bn * 4 + nt) * 64 + lane];
            acc[nt] = __builtin_amdgcn_mfma_f32_16x16x32_bf16(af.s, bf, acc[nt], 0, 0, 0);
        }
    }
    if (w == 0) {  // ks = 64 tail
        float xv[8];
        #pragma unroll
        for (int e = 0; e < 8; ++e) {
            int q = g * 8 + e;
            int csrc = (q < 4) ? (2048 + q) : (q - 4);
            xv[e] = xrow[csrc];
        }
        union { short8 s; unsigned int u[4]; } af;
        af.u[0] = pk2bf(xv[0], xv[1]);
        af.u[1] = pk2bf(xv[2], xv[3]);
        af.u[2] = pk2bf(xv[4], xv[5]);
        af.u[3] = pk2bf(xv[6], xv[7]);
        #pragma unroll
        for (int nt = 0; nt < 4; ++nt) {
            short8 bf = ((const short8*)wvp)[(size_t)(64 * 16 + bn * 4 + nt) * 64 + lane];
            acc[nt] = __builtin_amdgcn_mfma_f32_16x16x32_bf16(af.s, bf, acc[nt], 0, 0, 0);
        }
    }
    #pragma unroll
    for (int nt = 0; nt < 4; ++nt) red[w][nt][lane] = acc[nt];
    __syncthreads();

    {
        int nt = tid >> 7;
        int l  = tid & 63;
        int half = (tid >> 6) & 1;
        float r0 = 0.f, r1 = 0.f;
        #pragma unroll
        for (int ww = 0; ww < 8; ++ww) {
            f32x4 v = red[ww][nt][l];
            r0 += v[half * 2 + 0];
            r1 += v[half * 2 + 1];
        }
        int gg = l >> 4, jj = l & 15;
        int n = n0 + nt * 16 + jj;
        float base = bv[n] + bq[n] + Qpp[b * 256 + n] + Qpp[(4 + b) * 256 + n]
                   + Qpp[(8 + b) * 256 + n] + Qpp[(12 + b) * 256 + n];
        int row0 = i0 + gg * 4 + half * 2;
        Xp[((b * NR) + row0) * CC + n]       = r0 + base;
        Xp[((b * NR) + row0 + 1) * CC + n]   = r1 + base;
    }
}

// ---------------- fused 3-layer MLP over pairs, 32x32x16 MFMA, upper-tri, sums only ----------------
// block = (b, it in [0,64), jt in [it/8, 8)): 4 waves, wave = i = it*4+wave, j-tile 32.
// Emits colpart[(br4b)*256+j][it] and rowpart[(br4b)*256+i][jt] of exp(2h); h never stored.
// __launch_bounds__(256,2): 2nd arg = min BLOCKS/CU on this toolchain -> 8 waves -> 256 VGPR cap.
__global__ __launch_bounds__(256, 2) void pairs_kernel(
    const float* __restrict__ Xp,
    const unsigned short* __restrict__ wpa,
    const unsigned short* __restrict__ wpb,
    const float* __restrict__ b01, const float* __restrict__ b02,
    const float* __restrict__ b03,
    const float* __restrict__ b1,  const float* __restrict__ b2,
    const float* __restrict__ b3,
    const float* __restrict__ W03, const float* __restrict__ W3,
    float* __restrict__ colpart, float* __restrict__ rowpart)
{
    __shared__ __align__(16) unsigned short lds_wa[32768];   // 64 KB: one branch's L1 weights
    __shared__ __align__(16) float lds_si[1024];             // 4 i-rows of Xp
    __shared__ __align__(16) float lds_bias1[128];
    __shared__ __align__(16) float lds_bias2[64];
    __shared__ __align__(16) float lds_w3[64];
    __shared__ float lds_c[4][33];                           // per-wave col contributions

    const int tid = threadIdx.x;
    const int wave = tid >> 6;
    const int lane = tid & 63;
    const int hi = lane >> 5;        // 0/1: k-subgroup
    const int j32 = lane & 31;

    // grid decode: bx -> (b, it, jt), 288 tiles per b; it in [0,64), jt in [it/8, 8)
    int bx = blockIdx.x;
    int b = bx / 288;
    int u = bx - b * 288;
    int k = 0, off = 0;
    while (u >= off + 8 * (8 - k)) { off += 8 * (8 - k); ++k; }
    int rel = u - off, wdt = 8 - k;
    int it = k * 8 + rel / wdt;
    int jt = k + rel % wdt;

    const int i0 = it * 4;
    const int i = i0 + wave;
    const int j0 = jt * 32;
    const int br4base = b;           // br*4+b per branch

    // stage the 4 i-rows
    {
        int ww = tid >> 6, c4 = (tid & 63) * 4;
        *(float4*)&lds_si[ww * 256 + c4] =
            *(const float4*)&Xp[((b * NR) + (i0 + ww)) * CC + c4];
    }
    __syncthreads();

    // ---- build B-fragments of P^T ONCE (branch-independent) ----
    // lane: j = j0 + (l&31), k = 16*ks + 8*hi + e
    const float* xr = Xp + ((size_t)(b * NR) + (j0 + j32)) * CC;
    const float* si = lds_si + wave * 256;
    short8 bfr[16];
    #pragma unroll
    for (int ks = 0; ks < 16; ++ks) {
        const int c0 = ks * 16 + hi * 8;
        float4 xa = *(const float4*)(xr + c0);
        float4 xb = *(const float4*)(xr + c0 + 4);
        float4 sa = *(const float4*)(si + c0);
        float4 sb = *(const float4*)(si + c0 + 4);
        union { short8 s; unsigned int u[4]; } f;
        f.u[0] = pk2bf(xa.x * sa.x, xa.y * sa.y);
        f.u[1] = pk2bf(xa.z * sa.z, xa.w * sa.w);
        f.u[2] = pk2bf(xb.x * sb.x, xb.y * sb.y);
        f.u[3] = pk2bf(xb.z * sb.z, xb.w * sb.w);
        bfr[ks] = f.s;
    }

    for (int br = 0; br < 2; ++br) {
        __syncthreads();   // prior-branch lds_wa/bias/lds_c reads done
        {
            const uint4* gsrc = (const uint4*)(wpa + br * 32768);
            uint4* sdst = (uint4*)lds_wa;
            #pragma unroll
            for (int kk = 0; kk < 16; ++kk) sdst[kk * 256 + tid] = gsrc[kk * 256 + tid];
            if (tid < 128) lds_bias1[tid] = br ? b1[tid] : b01[tid];
            else if (tid < 192) lds_bias2[tid - 128] = br ? b2[tid - 128] : b02[tid - 128];
            else lds_w3[tid - 192] = br ? W3[tid - 192] : W03[tid - 192];
        }
        __syncthreads();
        const float b3v = br ? b3[0] : b03[0];

        // ---- layer 1: acc1[nt1] = (W1^T @ P^T) 32x32 tiles, C-init = bias1 ----
        // C/D: col j = l&31, row = (reg&3) + 8*(reg>>2) + 4*hi (+32*nt1)
        f32x16 acc1[4];
        #pragma unroll
        for (int nt = 0; nt < 4; ++nt) {
            #pragma unroll
            for (int q = 0; q < 4; ++q) {
                f32x4 bb = *(const f32x4*)&lds_bias1[nt * 32 + q * 8 + hi * 4];
                acc1[nt][q * 4 + 0] = bb[0];
                acc1[nt][q * 4 + 1] = bb[1];
                acc1[nt][q * 4 + 2] = bb[2];
                acc1[nt][q * 4 + 3] = bb[3];
            }
        }
        #pragma unroll
        for (int ks = 0; ks < 16; ++ks) {
            #pragma unroll
            for (int nt = 0; nt < 4; ++nt) {
                short8 wf = ((const short8*)lds_wa)[(nt * 16 + ks) * 64 + lane];
                acc1[nt] = __builtin_amdgcn_mfma_f32_32x32x16_bf16(wf, bfr[ks], acc1[nt], 0, 0, 0);
            }
        }

        // ---- layer 2: relu + pack + lane^32 exchange -> B-frag; W2^T frags from L2 ----
        f32x16 acc2[2];
        #pragma unroll
        for (int nt = 0; nt < 2; ++nt) {
            #pragma unroll
            for (int q = 0; q < 4; ++q) {
                f32x4 bb = *(const f32x4*)&lds_bias2[nt * 32 + q * 8 + hi * 4];
                acc2[nt][q * 4 + 0] = bb[0];
                acc2[nt][q * 4 + 1] = bb[1];
                acc2[nt][q * 4 + 2] = bb[2];
                acc2[nt][q * 4 + 3] = bb[3];
            }
        }
        const short8* wb = (const short8*)wpb + (size_t)br * 16 * 64;
        #pragma unroll
        for (int t = 0; t < 4; ++t) {
            #pragma unroll
            for (int s = 0; s < 2; ++s) {
                const int bse = s * 8;
                float rA0 = fmaxf(acc1[t][bse + 0], 0.f), rA1 = fmaxf(acc1[t][bse + 1], 0.f);
                float rA2 = fmaxf(acc1[t][bse + 2], 0.f), rA3 = fmaxf(acc1[t][bse + 3], 0.f);
                float rB0 = fmaxf(acc1[t][bse + 4], 0.f), rB1 = fmaxf(acc1[t][bse + 5], 0.f);
                float rB2 = fmaxf(acc1[t][bse + 6], 0.f), rB3 = fmaxf(acc1[t][bse + 7], 0.f);
                unsigned int uA0 = pk2bf(rA0, rA1), uA1 = pk2bf(rA2, rA3);
                unsigned int uB0 = pk2bf(rB0, rB1), uB1 = pk2bf(rB2, rB3);
                unsigned int pA0 = __shfl_xor(uA0, 32, 64), pA1 = __shfl_xor(uA1, 32, 64);
                unsigned int pB0 = __shfl_xor(uB0, 32, 64), pB1 = __shfl_xor(uB1, 32, 64);
                union { short8 s8; unsigned int u[4]; } B2;
                B2.u[0] = hi ? pB0 : uA0;
                B2.u[1] = hi ? pB1 : uA1;
                B2.u[2] = hi ? uB0 : pA0;
                B2.u[3] = hi ? uB1 : pA1;
                const int ks2 = 2 * t + s;
                #pragma unroll
                for (int nt = 0; nt < 2; ++nt) {
                    short8 wf2 = wb[(nt * 8 + ks2) * 64 + lane];
                    acc2[nt] = __builtin_amdgcn_mfma_f32_32x32x16_bf16(wf2, B2.s8, acc2[nt], 0, 0, 0);
                }
            }
        }

        // ---- layer 3: per-lane partial dot, reduce across hi pair ----
        float part = 0.f;
        #pragma unroll
        for (int nt = 0; nt < 2; ++nt) {
            #pragma unroll
            for (int q = 0; q < 4; ++q) {
                f32x4 wv = *(const f32x4*)&lds_w3[nt * 32 + q * 8 + hi * 4];
                part += fmaxf(acc2[nt][q * 4 + 0], 0.f) * wv[0];
                part += fmaxf(acc2[nt][q * 4 + 1], 0.f) * wv[1];
                part += fmaxf(acc2[nt][q * 4 + 2], 0.f) * wv[2];
                part += fmaxf(acc2[nt][q * 4 + 3], 0.f) * wv[3];
            }
        }
        part += __shfl_xor(part, 32, 64);          // lanes l and l^32 now both hold full dot
        const float h3 = fmaxf(part + b3v, 0.f);
        const float E = __expf(2.f * h3);
        const int j = j0 + j32;
        const float Ec = (j >= i) ? E : 0.f;       // col contribution (incl diag)
        float Er = (j >  i) ? E : 0.f;             // row contribution (strict upper)

        // row reduce: values duplicated across hi halves -> 64-lane sum = 2x row sum
        Er += __shfl_xor(Er, 1, 64);
        Er += __shfl_xor(Er, 2, 64);
        Er += __shfl_xor(Er, 4, 64);
        Er += __shfl_xor(Er, 8, 64);
        Er += __shfl_xor(Er, 16, 64);
        Er += __shfl_xor(Er, 32, 64);
        if (lane == 0)
            rowpart[((size_t)(br * 4 + br4base) * NR + i) * 8 + jt] = 0.5f * Er;

        if (!hi) lds_c[wave][j32] = Ec;
        __syncthreads();
        if (tid < 32) {
            float c = lds_c[0][tid] + lds_c[1][tid] + lds_c[2][tid] + lds_c[3][tid];
            colpart[((size_t)(br * 4 + br4base) * NR + (j0 + tid)) * 64 + it] = c;
        }
    }
}

// ---------------- colsum[j] = colpart-sum + rowpart-sum (symmetry); wn = colsum/Z ----------------
__global__ __launch_bounds__(256) void colsoft_final_kernel(
    const float* __restrict__ colpart, const float* __restrict__ rowpart,
    float* __restrict__ wn)
{
    const int blk = blockIdx.x;        // 0..7 = br*4+b
    const int j = threadIdx.x;
    const int jt = j >> 5;
    float cs = 0.f;
    const float* cp = colpart + ((size_t)blk * NR + j) * 64;
    const int itmax = 8 * jt + 8;      // launched its: it <= 8*jt+7
    for (int it2 = 0; it2 < itmax; ++it2) cs += cp[it2];
    const float* rp = rowpart + ((size_t)blk * NR + j) * 8;
    for (int q = j >> 5; q < 8; ++q) cs += rp[q];

    __shared__ float red[256];
    red[j] = cs; __syncthreads();
    for (int s = 128; s > 0; s >>= 1) {
        if (j < s) red[j] += red[j + s];
        __syncthreads();
    }
    wn[blk * 256 + j] = cs / red[0];
}

// ---------------- agg stage 1: partial weighted sums over j-chunks ----------------
__global__ __launch_bounds__(256) void agg_part_kernel(
    const float* __restrict__ X, const float* __restrict__ wn,
    float* __restrict__ apart)
{
    const int dc = blockIdx.x, b = blockIdx.y, jc = blockIdx.z;
    const int d = dc * 256 + threadIdx.x;
    __shared__ float wc[32];
    if (threadIdx.x < 32) {
        int j = jc * 32 + threadIdx.x;
        wc[threadIdx.x] = 0.5f * (wn[b * 256 + j] + wn[(4 + b) * 256 + j]);
    }
    __syncthreads();
    if (d < 2052) {
        const float* xp = X + (size_t)b * NR * 2052 + (size_t)jc * 32 * 2052 + d;
        float a0 = 0.f, a1 = 0.f, a2 = 0.f, a3 = 0.f;
        for (int r = 0; r < 32; r += 4) {
            a0 += wc[r + 0] * xp[(size_t)(r + 0) * 2052];
            a1 += wc[r + 1] * xp[(size_t)(r + 1) * 2052];
            a2 += wc[r + 2] * xp[(size_t)(r + 2) * 2052];
            a3 += wc[r + 3] * xp[(size_t)(r + 3) * 2052];
        }
        apart[(size_t)(jc * 4 + b) * 2304 + d] = (a0 + a1) + (a2 + a3);
    }
}

// ---------------- agg stage 2: sum partials ----------------
__global__ __launch_bounds__(256) void agg_final_kernel(
    const float* __restrict__ apart, float* __restrict__ out)
{
    const int dc = blockIdx.x, b = blockIdx.y;
    const int d = dc * 256 + threadIdx.x;
    if (d < 2052) {
        float s = 0.f;
        #pragma unroll
        for (int jc = 0; jc < 8; ++jc) s += apart[(size_t)(jc * 4 + b) * 2304 + d];
        out[b * 2052 + d] = s;
    }
}

extern "C" void kernel_launch(void* const* d_in, const int* in_sizes, int n_in,
                              void* d_out, int out_size, void* d_ws, size_t ws_size,
                              hipStream_t stream) {
    const float* Q   = (const float*)d_in[0];
    const float* X   = (const float*)d_in[1];
    const float* Wv  = (const float*)d_in[2];
    const float* bv  = (const float*)d_in[3];
    const float* Wq  = (const float*)d_in[4];
    const float* bq  = (const float*)d_in[5];
    const float* W01 = (const float*)d_in[6];
    const float* b01 = (const float*)d_in[7];
    const float* W02 = (const float*)d_in[8];
    const float* b02 = (const float*)d_in[9];
    const float* W03 = (const float*)d_in[10];
    const float* b03 = (const float*)d_in[11];
    const float* W1  = (const float*)d_in[12];
    const float* b1  = (const float*)d_in[13];
    const float* W2  = (const float*)d_in[14];
    const float* b2  = (const float*)d_in[15];
    const float* W3  = (const float*)d_in[16];
    const float* b3  = (const float*)d_in[17];

    char* ws = (char*)d_ws;
    // aliases: wvp over colpart/rowpart (dead before pairs writes), apart over Xp (dead after pairs)
    float* Xp   = (float*)(ws + 0);              // 1,048,576 B
    float* Qpp  = (float*)(ws + 1048576);        //    16,384 B
    float* wn   = (float*)(ws + 1064960);        //     8,192 B
    unsigned short* wpa = (unsigned short*)(ws + 1073152);  // 131,072 B
    unsigned short* wpb = (unsigned short*)(ws + 1204224);  //  32,768 B
    float* colpart = (float*)(ws + 1236992);     // 524,288 B  [8][256][64]
    float* rowpart = (float*)(ws + 1761280);     //  65,536 B  [8][256][8] -> end 1,826,816
    unsigned short* wvp = (unsigned short*)(ws + 1236992);  // 1,064,960 B (aliased)
    float* apart = (float*)(ws + 0);             // 294,912 B (aliases Xp)
    float* out = (float*)d_out;

    qp_kernel<<<dim3(4, 4), 256, 0, stream>>>(Q, Wq, Qpp);
    wvp_pack_kernel<<<65, 256, 0, stream>>>(Wv, wvp);
    pack_kernel<<<320, 256, 0, stream>>>(W01, W1, W02, W2, wpa, wpb);
    xp_kernel<<<dim3(16, 4, 4), 512, 0, stream>>>(X, wvp, bv, bq, Qpp, Xp);
    pairs_kernel<<<1152, 256, 0, stream>>>(Xp, wpa, wpb, b01, b02, b03,
                                           b1, b2, b3, W03, W3, colpart, rowpart);
    colsoft_final_kernel<<<8, 256, 0, stream>>>(colpart, rowpart, wn);
    agg_part_kernel<<<dim3(9, 4, 8), 256, 0, stream>>>(X, wn, apart);
    agg_final_kernel<<<dim3(9, 4), 256, 0, stream>>>(apart, out);
}